// Round 1
// baseline (28859.091 us; speedup 1.0000x reference)
//
#include <hip/hip_runtime.h>
#include <stdint.h>

typedef _Float16 half_t;
typedef _Float16 half2v __attribute__((ext_vector_type(2)));
typedef _Float16 half8v __attribute__((ext_vector_type(8)));
typedef float    f32x4  __attribute__((ext_vector_type(4)));

#define Hd 512
#define Td 400
#define Sd 400
#define Bd 32

// ws layout (bytes)
#define OFF_BAR   0ull          // 4096: barrier cnt/gen per group
#define OFF_HBUF  4096ull       // f16 [2][32][512] = 65536
#define OFF_PH    69632ull      // f32 [8][4][512]  = 65536
#define OFF_GH    135168ull     // f32 [8][4][1536] = 196608
#define OFF_PC    331776ull     // f32 [8][4][8][512] = 524288
#define OFF_LB    856064ull     // f32 [8][4][8] = 1024
#define OFF_ENC   1048576ull    // f16 [400][32][512]
#define OFF_PENC  14155776ull   // f16 [400][32][512]
#define OFF_XS    27262976ull   // f16 [400][32][512]
#define OFF_GIX   40370176ull   // f16 [400][32][1536]
#define OFF_H2A   79691776ull   // f16 [400][32][512]
#define OFF_W1    92798976ull   // f16 [2048][512]  (fc_W rows 0-511, Whh rows 512-2047)
#define OFF_W3    94896128ull   // f16 [1536][512]  (Wih_c)
#define OFF_WX    96468992ull   // f16 [1536][512]  (Wih_x)
#define OFF_SPEC  98041856ull   // f16 [512][512]

#if __has_builtin(__builtin_amdgcn_fdot2)
#define FDOT2(a,b,c) __builtin_amdgcn_fdot2((a),(b),(c),false)
#else
static __device__ __forceinline__ float FDOT2(half2v a, half2v b, float c){
  return fmaf((float)a.x,(float)b.x, fmaf((float)a.y,(float)b.y,c));
}
#endif

static __device__ __forceinline__ float fast_tanh(float x){
  float t = __builtin_amdgcn_exp2f(x * 2.8853900817779268f);   // exp(2x)
  return fmaf(-2.f, __builtin_amdgcn_rcpf(t + 1.f), 1.f);
}
static __device__ __forceinline__ float fast_sigmoid(float x){
  float t = __builtin_amdgcn_exp2f(x * -1.4426950408889634f);  // exp(-x)
  return __builtin_amdgcn_rcpf(1.f + t);
}

// ---------------- init: zero barriers + h0 -------------------------------
__global__ void k_init(char* ws){
  unsigned* p = (unsigned*)ws;
  int i = blockIdx.x*blockDim.x + threadIdx.x;
  if (i < 17408) p[i] = 0u;   // [0,69632) bytes: barrier region + h_buf
}

// ---------------- prep: f32 -> f16 staging -------------------------------
__global__ void k_prep_enc(const float* __restrict__ src, half_t* __restrict__ dst, int n){
  int st = gridDim.x*blockDim.x;
  for (int i = blockIdx.x*blockDim.x + threadIdx.x; i < n; i += st)
    dst[i] = (half_t)src[i];
}
__global__ void k_prep_xs(const float* __restrict__ dec, half_t* __restrict__ dst){
  const int n = Td*Bd*Hd; int st = gridDim.x*blockDim.x;
  for (int i = blockIdx.x*blockDim.x + threadIdx.x; i < n; i += st){
    float v = (i < Bd*Hd) ? 0.f : dec[i - Bd*Hd];   // teacher forcing shift
    dst[i] = (half_t)v;
  }
}
__global__ void k_prep_w(const float* __restrict__ fcW, const float* __restrict__ Wih,
                         const float* __restrict__ Whh, const float* __restrict__ specW,
                         char* __restrict__ ws){
  half_t* w1 = (half_t*)(ws + OFF_W1);
  half_t* w3 = (half_t*)(ws + OFF_W3);
  half_t* wx = (half_t*)(ws + OFF_WX);
  half_t* sp = (half_t*)(ws + OFF_SPEC);
  int st = gridDim.x*blockDim.x;
  int t0 = blockIdx.x*blockDim.x + threadIdx.x;
  for (int i = t0; i < 2048*512; i += st)
    w1[i] = (half_t)((i < 512*512) ? fcW[i] : Whh[i - 512*512]);
  for (int i = t0; i < 1536*512; i += st){
    int r = i >> 9, k = i & 511;
    wx[i] = (half_t)Wih[r*1024 + k];
    w3[i] = (half_t)Wih[r*1024 + 512 + k];
  }
  for (int i = t0; i < 512*512; i += st) sp[i] = (half_t)specW[i];
}

// ---------------- bulk MFMA GEMM: C[M,N] = A[M,512] @ W[N,512]^T ---------
// MODE 0: out f16 row-major [M][N].  MODE 1: out f32 mels (B,T,H) + bias.
template<int MODE>
__global__ __launch_bounds__(256) void k_gemm(const half_t* __restrict__ A,
                                              const half_t* __restrict__ W,
                                              void* __restrict__ out, int N,
                                              const float* __restrict__ bias)
{
  __shared__ __align__(16) half_t As[64*32];
  __shared__ __align__(16) half_t Ws[64*32];
  const int tid = threadIdx.x;
  const int m0 = blockIdx.y * 64, n0 = blockIdx.x * 64;
  const int trow = tid >> 2, tseg = tid & 3;
  const int wv = tid >> 6, ln = tid & 63;
  const int fr = ln & 15, ko = (ln >> 4) * 8;
  f32x4 acc[4];
  #pragma unroll
  for (int cb = 0; cb < 4; ++cb){ acc[cb][0]=0.f; acc[cb][1]=0.f; acc[cb][2]=0.f; acc[cb][3]=0.f; }
  for (int kk = 0; kk < 512; kk += 32){
    ((uint4*)As)[tid] = *(const uint4*)(A + (size_t)(m0 + trow)*512 + kk + tseg*8);
    ((uint4*)Ws)[tid] = *(const uint4*)(W + (size_t)(n0 + trow)*512 + kk + tseg*8);
    __syncthreads();
    half8v af = *(const half8v*)&As[(wv*16 + fr)*32 + ko];
    #pragma unroll
    for (int cb = 0; cb < 4; ++cb){
      half8v bf = *(const half8v*)&Ws[(cb*16 + fr)*32 + ko];
      acc[cb] = __builtin_amdgcn_mfma_f32_16x16x32_f16(af, bf, acc[cb], 0, 0, 0);
    }
    __syncthreads();
  }
  #pragma unroll
  for (int cb = 0; cb < 4; ++cb){
    #pragma unroll
    for (int i = 0; i < 4; ++i){
      int gr = m0 + wv*16 + (ln >> 4)*4 + i;   // C row = A row   (m89 C/D layout)
      int gc = n0 + cb*16 + (ln & 15);         // C col
      if (MODE == 0){
        ((half_t*)out)[(size_t)gr*N + gc] = (half_t)acc[cb][i];
      } else {
        int tt = gr >> 5, bb = gr & 31;        // row = t*32+b -> (b,t,h)
        ((float*)out)[(size_t)bb*(Td*Hd) + (size_t)tt*Hd + gc] = acc[cb][i] + bias[gc];
      }
    }
  }
}

// ---------------- gate projection ---------------------------------------
__global__ __launch_bounds__(256) void k_gate(const half_t* __restrict__ h2a,
    const float* __restrict__ gW, const float* __restrict__ gb, float* __restrict__ out)
{
  const int o = blockIdx.x * 4 + (threadIdx.x >> 6);   // o = t*32+b
  const int lane = threadIdx.x & 63;
  const half8v hv = *(const half8v*)(h2a + (size_t)o*512 + lane*8);
  float a = 0.f;
  #pragma unroll
  for (int i = 0; i < 8; ++i) a = fmaf((float)hv[i], gW[lane*8 + i], a);
  #pragma unroll
  for (int o2 = 1; o2 < 64; o2 <<= 1) a += __shfl_xor(a, o2);
  if (lane == 0){
    const int tt = o >> 5, bb = o & 31;
    out[Bd*Td*Hd + bb*Td + tt] = a + gb[0];
  }
}

// ---------------- group barrier (32 blocks, device-scope atomics) --------
static __device__ __forceinline__ void gbar(unsigned* cnt, unsigned* gen, unsigned target){
  __syncthreads();
  if (threadIdx.x == 0){
    __threadfence();
    unsigned prev = __hip_atomic_fetch_add(cnt, 1u, __ATOMIC_ACQ_REL, __HIP_MEMORY_SCOPE_AGENT);
    if (prev == 31u){
      __hip_atomic_store(cnt, 0u, __ATOMIC_RELAXED, __HIP_MEMORY_SCOPE_AGENT);
      __hip_atomic_fetch_add(gen, 1u, __ATOMIC_RELEASE, __HIP_MEMORY_SCOPE_AGENT);
    } else {
      while (__hip_atomic_load(gen, __ATOMIC_ACQUIRE, __HIP_MEMORY_SCOPE_AGENT) < target)
        __builtin_amdgcn_s_sleep(4);
    }
    __threadfence();
  }
  __syncthreads();
}

// ---------------- persistent recurrent kernel ----------------------------
// 256 blocks x 512 thr. group g = blockIdx%8 (XCD), member m = blockIdx/8 (0..31).
// Group owns batches b0..b0+3. 3 group barriers per step.
__global__ __launch_bounds__(512, 2) void k_main(char* __restrict__ ws,
                                                 const float* __restrict__ attw)
{
  const int g = blockIdx.x & 7;
  const int m = blockIdx.x >> 3;
  const int tid = threadIdx.x;
  const int lane = tid & 63;
  const int b0 = g * 4;

  half_t* hbuf = (half_t*)(ws + OFF_HBUF);
  float*  ph   = (float*)(ws + OFF_PH) + g * (4*512);
  float*  gh   = (float*)(ws + OFF_GH) + g * (4*1536);
  float*  pc   = (float*)(ws + OFF_PC) + g * (4*8*512);
  float*  lb   = (float*)(ws + OFF_LB) + g * 32;
  const half_t* Penc = (const half_t*)(ws + OFF_PENC);
  const half_t* ench = (const half_t*)(ws + OFF_ENC);
  const half_t* gix  = (const half_t*)(ws + OFF_GIX);
  half_t* h2a  = (half_t*)(ws + OFF_H2A);
  const half_t* w1 = (const half_t*)(ws + OFF_W1);
  const half_t* w3 = (const half_t*)(ws + OFF_W3);
  unsigned* cnt = (unsigned*)(ws + OFF_BAR) + g * 32;
  unsigned* gen = (unsigned*)(ws + OFF_BAR + 2048ull) + g * 32;

  __shared__ __align__(16) half_t hs[4*512];
  __shared__ __align__(16) half_t ctxs[4*512];
  __shared__ float es[64];
  __shared__ float gis[4][3][16];
  __shared__ float Ls[4];

  // --- persistent register-resident weight slices -------------------------
  // phase1: rows of [fc_W;Whh]: member owns 64 rows, 8 threads/row, 64 halfs each
  const int r1 = tid >> 3, p = tid & 7;
  half2v w1r[32];
  {
    const half_t* wp = w1 + (size_t)(m*64 + r1) * 512;
    #pragma unroll
    for (int i = 0; i < 32; ++i) w1r[i] = *(const half2v*)(wp + 2*(p + 8*i));
  }
  // phase3: Wih_c rows {gate*512 + m*16 + j} for j in [0,16), 48 rows, 8 thr/row
  const int gate3 = r1 >> 4, j3 = r1 & 15;   // valid when r1<48
  half2v w3r[32];
  {
    half2v z; z.x = (_Float16)0; z.y = (_Float16)0;
    #pragma unroll
    for (int i = 0; i < 32; ++i) w3r[i] = z;
    if (r1 < 48){
      const half_t* wp = w3 + (size_t)(gate3*512 + m*16 + j3) * 512;
      #pragma unroll
      for (int i = 0; i < 32; ++i) w3r[i] = *(const half2v*)(wp + 2*(p + 8*i));
    }
  }
  float awr[8];
  #pragma unroll
  for (int i = 0; i < 8; ++i) awr[i] = attw[lane*8 + i];

  const int b_l = m & 3, ch = m >> 2;          // phase2 role: batch b_l, s-chunk ch
  const int bglob = b0 + b_l;
  unsigned bt = 0;

  for (int t = 0; t < Td; ++t){
    const int cur = t & 1, nxt = cur ^ 1;
    // ---------- phase 1: Ph = fc_W@h, gh = Whh@h (per group's 4 b) --------
    ((uint2*)hs)[tid] = ((const uint2*)(hbuf + (size_t)cur*(32*512) + b0*512))[tid];
    __syncthreads();
    {
      const half2v* h2p = (const half2v*)hs;
      float a0=0.f,a1=0.f,a2=0.f,a3=0.f;
      #pragma unroll
      for (int i = 0; i < 32; ++i){
        half2v wv = w1r[i];
        int idx = p + 8*i;
        a0 = FDOT2(wv, h2p[idx],       a0);
        a1 = FDOT2(wv, h2p[256 + idx], a1);
        a2 = FDOT2(wv, h2p[512 + idx], a2);
        a3 = FDOT2(wv, h2p[768 + idx], a3);
      }
      #pragma unroll
      for (int o = 1; o < 8; o <<= 1){
        a0 += __shfl_xor(a0, o); a1 += __shfl_xor(a1, o);
        a2 += __shfl_xor(a2, o); a3 += __shfl_xor(a3, o);
      }
      if (p == 0){
        int R = m*64 + r1;
        if (R < 512){
          ph[0*512+R]=a0; ph[1*512+R]=a1; ph[2*512+R]=a2; ph[3*512+R]=a3;
        } else {
          int Rw = R - 512;
          gh[0*1536+Rw]=a0; gh[1*1536+Rw]=a1; gh[2*1536+Rw]=a2; gh[3*1536+Rw]=a3;
        }
      }
    }
    gbar(cnt, gen, ++bt);
    // ---------- phase 2: attention scores + chunk-local softmax partials --
    {
      const float4* pp4 = (const float4*)&ph[b_l*512 + lane*8];
      float4 qa = pp4[0], qb = pp4[1];
      float phr[8] = {qa.x,qa.y,qa.z,qa.w, qb.x,qb.y,qb.z,qb.w};
      const int w = tid >> 6;
      const int ns = (w < 2) ? 7 : 6;                      // 50 = 2*7 + 6*6
      const half_t* pbase = Penc + ((size_t)(ch*50)*32 + bglob)*512 + lane*8;
      half8v pv = *(const half8v*)(pbase + (size_t)w*16384);
      for (int k = 0; k < ns; ++k){
        int s_l = w + 8*k;
        half8v cv = pv;
        if (k + 1 < ns) pv = *(const half8v*)(pbase + (size_t)(s_l+8)*16384);
        float a = 0.f;
        #pragma unroll
        for (int i = 0; i < 8; ++i){
          float x = (float)cv[i] + phr[i];
          a = fmaf(fast_tanh(x), awr[i], a);
        }
        #pragma unroll
        for (int o = 1; o < 64; o <<= 1) a += __shfl_xor(a, o);
        if (lane == 0) es[s_l] = a;
      }
      __syncthreads();
      if (tid < 64){
        float ev = 0.f;
        if (tid < 50){
          ev = __builtin_amdgcn_exp2f((es[tid] - 20.f) * 1.4426950408889634f);
          es[tid] = ev;   // fixed-offset softmax weight (|e| <= ||att_w||_1 ~ 18)
        }
        #pragma unroll
        for (int o = 1; o < 64; o <<= 1) ev += __shfl_xor(ev, o);
        if (tid == 0) lb[b_l*8 + ch] = ev;
      }
      __syncthreads();
      float acc2 = 0.f;
      const half_t* ep = ench + ((size_t)(ch*50)*32 + bglob)*512 + tid;
      #pragma unroll 5
      for (int s_l = 0; s_l < 50; ++s_l)
        acc2 = fmaf((float)ep[(size_t)s_l*16384], es[s_l], acc2);
      pc[(b_l*8 + ch)*512 + tid] = acc2;
    }
    gbar(cnt, gen, ++bt);
    // ---------- phase 3: combine ctx, gi_c = Wih_c@ctx, GRU update --------
    if (tid < 4){
      float L = 0.f;
      #pragma unroll
      for (int c2 = 0; c2 < 8; ++c2) L += lb[tid*8 + c2];
      Ls[tid] = __builtin_amdgcn_rcpf(L);
    }
    __syncthreads();
    #pragma unroll
    for (int rep = 0; rep < 4; ++rep){
      int idx = rep*512 + tid;
      int bb = idx >> 9, hh = idx & 511;
      float v = 0.f;
      #pragma unroll
      for (int c2 = 0; c2 < 8; ++c2) v += pc[(bb*8 + c2)*512 + hh];
      ctxs[bb*512 + hh] = (half_t)(v * Ls[bb]);
    }
    __syncthreads();
    if (r1 < 48){
      const half2v* cx = (const half2v*)ctxs;
      float a0=0.f,a1=0.f,a2=0.f,a3=0.f;
      #pragma unroll
      for (int i = 0; i < 32; ++i){
        half2v wv = w3r[i];
        int idx = p + 8*i;
        a0 = FDOT2(wv, cx[idx],       a0);
        a1 = FDOT2(wv, cx[256 + idx], a1);
        a2 = FDOT2(wv, cx[512 + idx], a2);
        a3 = FDOT2(wv, cx[768 + idx], a3);
      }
      #pragma unroll
      for (int o = 1; o < 8; o <<= 1){
        a0 += __shfl_xor(a0, o); a1 += __shfl_xor(a1, o);
        a2 += __shfl_xor(a2, o); a3 += __shfl_xor(a3, o);
      }
      if (p == 0){
        gis[0][gate3][j3] = a0; gis[1][gate3][j3] = a1;
        gis[2][gate3][j3] = a2; gis[3][gate3][j3] = a3;
      }
    }
    __syncthreads();
    if (tid < 64){
      int bl = tid >> 4, jl = tid & 15;
      int j = m*16 + jl;
      int bg = b0 + bl;
      const half_t* gp = gix + ((size_t)t*32 + bg)*1536;
      float xr = (float)gp[j]          + gis[bl][0][jl] + gh[bl*1536 + j];
      float xz = (float)gp[512 + j]    + gis[bl][1][jl] + gh[bl*1536 + 512 + j];
      float xn = (float)gp[1024 + j]   + gis[bl][2][jl];
      float gn_h = gh[bl*1536 + 1024 + j];
      float r = fast_sigmoid(xr);
      float z = fast_sigmoid(xz);
      float n = fast_tanh(xn + r * gn_h);
      float hold = (float)hbuf[(size_t)cur*(32*512) + bg*512 + j];
      float h2v = (1.f - z) * n + z * hold;
      hbuf[(size_t)nxt*(32*512) + bg*512 + j] = (half_t)h2v;
      h2a[((size_t)t*32 + bg)*512 + j] = (half_t)h2v;
    }
    gbar(cnt, gen, ++bt);
  }
}

// ---------------- launch --------------------------------------------------
extern "C" void kernel_launch(void* const* d_in, const int* in_sizes, int n_in,
                              void* d_out, int out_size, void* d_ws, size_t ws_size,
                              hipStream_t stream)
{
  const float* dec   = (const float*)d_in[0];
  const float* enc   = (const float*)d_in[1];
  const float* fcW   = (const float*)d_in[2];
  const float* attw  = (const float*)d_in[3];
  const float* Wih   = (const float*)d_in[4];
  const float* Whh   = (const float*)d_in[5];
  const float* specW = (const float*)d_in[6];
  const float* specb = (const float*)d_in[7];
  const float* gateW = (const float*)d_in[8];
  const float* gateb = (const float*)d_in[9];
  char* ws = (char*)d_ws;
  float* out = (float*)d_out;

  hipLaunchKernelGGL(k_init, dim3(68), dim3(256), 0, stream, ws);
  hipLaunchKernelGGL(k_prep_enc, dim3(2048), dim3(256), 0, stream,
                     enc, (half_t*)(ws + OFF_ENC), Sd*Bd*Hd);
  hipLaunchKernelGGL(k_prep_xs, dim3(2048), dim3(256), 0, stream,
                     dec, (half_t*)(ws + OFF_XS));
  hipLaunchKernelGGL(k_prep_w, dim3(1024), dim3(256), 0, stream,
                     fcW, Wih, Whh, specW, ws);
  // Penc = enc @ fc_W^T   (M=12800, N=512)
  hipLaunchKernelGGL((k_gemm<0>), dim3(8, 200), dim3(256), 0, stream,
                     (const half_t*)(ws + OFF_ENC), (const half_t*)(ws + OFF_W1),
                     (void*)(ws + OFF_PENC), 512, (const float*)nullptr);
  // GI_x = xs @ Wih_x^T   (M=12800, N=1536)
  hipLaunchKernelGGL((k_gemm<0>), dim3(24, 200), dim3(256), 0, stream,
                     (const half_t*)(ws + OFF_XS), (const half_t*)(ws + OFF_WX),
                     (void*)(ws + OFF_GIX), 1536, (const float*)nullptr);
  // recurrent loop
  hipLaunchKernelGGL(k_main, dim3(256), dim3(512), 0, stream, ws, attw);
  // mels = h2 @ spec_W^T + b, written (B,T,H)
  hipLaunchKernelGGL((k_gemm<1>), dim3(8, 200), dim3(256), 0, stream,
                     (const half_t*)(ws + OFF_H2A), (const half_t*)(ws + OFF_SPEC),
                     (void*)out, 512, specb);
  // gates = h2 @ gate_W + b, written (B,T)
  hipLaunchKernelGGL(k_gate, dim3(3200), dim3(256), 0, stream,
                     (const half_t*)(ws + OFF_H2A), gateW, gateb, out);
}

// Round 2
// 4721.749 us; speedup vs baseline: 6.1119x; 6.1119x over previous
//
#include <hip/hip_runtime.h>
#include <stdint.h>

typedef _Float16 half_t;
typedef _Float16 half2v __attribute__((ext_vector_type(2)));
typedef _Float16 half8v __attribute__((ext_vector_type(8)));
typedef float    f32x4  __attribute__((ext_vector_type(4)));
typedef float    f32x2  __attribute__((ext_vector_type(2)));

#define Hd 512
#define Td 400
#define Sd 400
#define Bd 32

// ws layout (bytes)
#define OFF_BAR   0ull          // 4096: barrier cnt per group (128B stride)
#define OFF_HBUF  4096ull       // f16 [2][32][512] = 65536
#define OFF_PH    69632ull      // f32 [8][4][512]  = 65536
#define OFF_GH    135168ull     // f32 [8][4][1536] = 196608
#define OFF_PC    331776ull     // f32 [8][4][8][512] = 524288
#define OFF_LB    856064ull     // f32 [8][4][8] = 1024
#define OFF_ENC   1048576ull    // f16 [400][32][512]
#define OFF_PENC  14155776ull   // f16 [400][32][512]
#define OFF_XS    27262976ull   // f16 [400][32][512]
#define OFF_GIX   40370176ull   // f16 [400][32][1536]
#define OFF_H2A   79691776ull   // f16 [400][32][512]
#define OFF_W1    92798976ull   // f16 [2048][512]  (fc_W rows 0-511, Whh rows 512-2047)
#define OFF_W3    94896128ull   // f16 [1536][512]  (Wih_c)
#define OFF_WX    96468992ull   // f16 [1536][512]  (Wih_x)
#define OFF_SPEC  98041856ull   // f16 [512][512]

#if __has_builtin(__builtin_amdgcn_fdot2)
#define FDOT2(a,b,c) __builtin_amdgcn_fdot2((a),(b),(c),false)
#else
static __device__ __forceinline__ float FDOT2(half2v a, half2v b, float c){
  return fmaf((float)a.x,(float)b.x, fmaf((float)a.y,(float)b.y,c));
}
#endif

static __device__ __forceinline__ float fast_tanh(float x){
  float t = __builtin_amdgcn_exp2f(x * 2.8853900817779268f);   // exp(2x)
  return fmaf(-2.f, __builtin_amdgcn_rcpf(t + 1.f), 1.f);
}
static __device__ __forceinline__ float fast_sigmoid(float x){
  float t = __builtin_amdgcn_exp2f(x * -1.4426950408889634f);  // exp(-x)
  return __builtin_amdgcn_rcpf(1.f + t);
}

// L1-bypassing (L2-reading) relaxed loads — no cache-maintenance codegen.
static __device__ __forceinline__ float ld_f32_l2(const float* p){
  return __hip_atomic_load(p, __ATOMIC_RELAXED, __HIP_MEMORY_SCOPE_AGENT);
}
static __device__ __forceinline__ unsigned long long ld_u64_l2(const void* p){
  return __hip_atomic_load((const unsigned long long*)p, __ATOMIC_RELAXED,
                           __HIP_MEMORY_SCOPE_AGENT);
}
static __device__ __forceinline__ f32x2 ld_f32x2_l2(const float* p){
  union { unsigned long long u; f32x2 f; } cv;
  cv.u = ld_u64_l2(p);
  return cv.f;
}

// ---------------- init: zero barriers + h0 -------------------------------
__global__ void k_init(char* ws){
  unsigned* p = (unsigned*)ws;
  int i = blockIdx.x*blockDim.x + threadIdx.x;
  if (i < 17408) p[i] = 0u;   // [0,69632) bytes: barrier region + h_buf
}

// ---------------- prep: f32 -> f16 staging -------------------------------
__global__ void k_prep_enc(const float* __restrict__ src, half_t* __restrict__ dst, int n){
  int st = gridDim.x*blockDim.x;
  for (int i = blockIdx.x*blockDim.x + threadIdx.x; i < n; i += st)
    dst[i] = (half_t)src[i];
}
__global__ void k_prep_xs(const float* __restrict__ dec, half_t* __restrict__ dst){
  const int n = Td*Bd*Hd; int st = gridDim.x*blockDim.x;
  for (int i = blockIdx.x*blockDim.x + threadIdx.x; i < n; i += st){
    float v = (i < Bd*Hd) ? 0.f : dec[i - Bd*Hd];   // teacher forcing shift
    dst[i] = (half_t)v;
  }
}
__global__ void k_prep_w(const float* __restrict__ fcW, const float* __restrict__ Wih,
                         const float* __restrict__ Whh, const float* __restrict__ specW,
                         char* __restrict__ ws){
  half_t* w1 = (half_t*)(ws + OFF_W1);
  half_t* w3 = (half_t*)(ws + OFF_W3);
  half_t* wx = (half_t*)(ws + OFF_WX);
  half_t* sp = (half_t*)(ws + OFF_SPEC);
  int st = gridDim.x*blockDim.x;
  int t0 = blockIdx.x*blockDim.x + threadIdx.x;
  for (int i = t0; i < 2048*512; i += st)
    w1[i] = (half_t)((i < 512*512) ? fcW[i] : Whh[i - 512*512]);
  for (int i = t0; i < 1536*512; i += st){
    int r = i >> 9, k = i & 511;
    wx[i] = (half_t)Wih[r*1024 + k];
    w3[i] = (half_t)Wih[r*1024 + 512 + k];
  }
  for (int i = t0; i < 512*512; i += st) sp[i] = (half_t)specW[i];
}

// ---------------- bulk MFMA GEMM: C[M,N] = A[M,512] @ W[N,512]^T ---------
// MODE 0: out f16 row-major [M][N].  MODE 1: out f32 mels (B,T,H) + bias.
template<int MODE>
__global__ __launch_bounds__(256) void k_gemm(const half_t* __restrict__ A,
                                              const half_t* __restrict__ W,
                                              void* __restrict__ out, int N,
                                              const float* __restrict__ bias)
{
  __shared__ __align__(16) half_t As[64*32];
  __shared__ __align__(16) half_t Ws[64*32];
  const int tid = threadIdx.x;
  const int m0 = blockIdx.y * 64, n0 = blockIdx.x * 64;
  const int trow = tid >> 2, tseg = tid & 3;
  const int wv = tid >> 6, ln = tid & 63;
  const int fr = ln & 15, ko = (ln >> 4) * 8;
  f32x4 acc[4];
  #pragma unroll
  for (int cb = 0; cb < 4; ++cb){ acc[cb][0]=0.f; acc[cb][1]=0.f; acc[cb][2]=0.f; acc[cb][3]=0.f; }
  for (int kk = 0; kk < 512; kk += 32){
    ((uint4*)As)[tid] = *(const uint4*)(A + (size_t)(m0 + trow)*512 + kk + tseg*8);
    ((uint4*)Ws)[tid] = *(const uint4*)(W + (size_t)(n0 + trow)*512 + kk + tseg*8);
    __syncthreads();
    half8v af = *(const half8v*)&As[(wv*16 + fr)*32 + ko];
    #pragma unroll
    for (int cb = 0; cb < 4; ++cb){
      half8v bf = *(const half8v*)&Ws[(cb*16 + fr)*32 + ko];
      acc[cb] = __builtin_amdgcn_mfma_f32_16x16x32_f16(af, bf, acc[cb], 0, 0, 0);
    }
    __syncthreads();
  }
  #pragma unroll
  for (int cb = 0; cb < 4; ++cb){
    #pragma unroll
    for (int i = 0; i < 4; ++i){
      int gr = m0 + wv*16 + (ln >> 4)*4 + i;   // C row = A row   (m89 C/D layout)
      int gc = n0 + cb*16 + (ln & 15);         // C col
      if (MODE == 0){
        ((half_t*)out)[(size_t)gr*N + gc] = (half_t)acc[cb][i];
      } else {
        int tt = gr >> 5, bb = gr & 31;        // row = t*32+b -> (b,t,h)
        ((float*)out)[(size_t)bb*(Td*Hd) + (size_t)tt*Hd + gc] = acc[cb][i] + bias[gc];
      }
    }
  }
}

// ---------------- gate projection ---------------------------------------
__global__ __launch_bounds__(256) void k_gate(const half_t* __restrict__ h2a,
    const float* __restrict__ gW, const float* __restrict__ gb, float* __restrict__ out)
{
  const int o = blockIdx.x * 4 + (threadIdx.x >> 6);   // o = t*32+b
  const int lane = threadIdx.x & 63;
  const half8v hv = *(const half8v*)(h2a + (size_t)o*512 + lane*8);
  float a = 0.f;
  #pragma unroll
  for (int i = 0; i < 8; ++i) a = fmaf((float)hv[i], gW[lane*8 + i], a);
  #pragma unroll
  for (int o2 = 1; o2 < 64; o2 <<= 1) a += __shfl_xor(a, o2);
  if (lane == 0){
    const int tt = o >> 5, bb = o & 31;
    out[Bd*Td*Hd + bb*Td + tt] = a + gb[0];
  }
}

// ---------------- group barrier: monotonic counter, relaxed atomics ------
// Same-XCD group (blockIdx%8 round-robin). Producer stores are write-through
// L1 -> L2; __syncthreads drains vmcnt, so data is L2-visible before arrive.
// Consumers read shared data with L1-bypassing (sc1) relaxed atomic loads.
// NO acq/rel => no buffer_wbl2 / buffer_inv L2 sweeps (the round-1 killer).
static __device__ __forceinline__ void gbar(unsigned* cnt, unsigned step){
  __syncthreads();
  __asm__ __volatile__("" ::: "memory");
  if (threadIdx.x == 0){
    __hip_atomic_fetch_add(cnt, 1u, __ATOMIC_RELAXED, __HIP_MEMORY_SCOPE_AGENT);
    const unsigned target = step * 32u;
    while (__hip_atomic_load(cnt, __ATOMIC_RELAXED, __HIP_MEMORY_SCOPE_AGENT) < target)
      __builtin_amdgcn_s_sleep(1);
  }
  __asm__ __volatile__("" ::: "memory");
  __syncthreads();
}

// ---------------- persistent recurrent kernel ----------------------------
// 256 blocks x 512 thr. group g = blockIdx%8 (XCD), member m = blockIdx/8 (0..31).
// Group owns batches b0..b0+3. 3 group barriers per step.
__global__ __launch_bounds__(512, 2) void k_main(char* __restrict__ ws,
                                                 const float* __restrict__ attw)
{
  const int g = blockIdx.x & 7;
  const int m = blockIdx.x >> 3;
  const int tid = threadIdx.x;
  const int lane = tid & 63;
  const int b0 = g * 4;

  half_t* hbuf = (half_t*)(ws + OFF_HBUF);
  float*  ph   = (float*)(ws + OFF_PH) + g * (4*512);
  float*  gh   = (float*)(ws + OFF_GH) + g * (4*1536);
  float*  pc   = (float*)(ws + OFF_PC) + g * (4*8*512);
  float*  lb   = (float*)(ws + OFF_LB) + g * 32;
  const half_t* Penc = (const half_t*)(ws + OFF_PENC);
  const half_t* ench = (const half_t*)(ws + OFF_ENC);
  const half_t* gix  = (const half_t*)(ws + OFF_GIX);
  half_t* h2a  = (half_t*)(ws + OFF_H2A);
  const half_t* w1 = (const half_t*)(ws + OFF_W1);
  const half_t* w3 = (const half_t*)(ws + OFF_W3);
  unsigned* cnt = (unsigned*)(ws + OFF_BAR) + g * 32;

  __shared__ __align__(16) half_t hs[4*512];
  __shared__ __align__(16) half_t ctxs[4*512];
  __shared__ float es[64];
  __shared__ float gis[4][3][16];
  __shared__ float Ls[4];

  // --- persistent register-resident weight slices -------------------------
  // phase1: rows of [fc_W;Whh]: member owns 64 rows, 8 threads/row, 64 halfs each
  const int r1 = tid >> 3, p = tid & 7;
  half2v w1r[32];
  {
    const half_t* wp = w1 + (size_t)(m*64 + r1) * 512;
    #pragma unroll
    for (int i = 0; i < 32; ++i) w1r[i] = *(const half2v*)(wp + 2*(p + 8*i));
  }
  // phase3: Wih_c rows {gate*512 + m*16 + j} for j in [0,16), 48 rows, 8 thr/row
  const int gate3 = r1 >> 4, j3 = r1 & 15;   // valid when r1<48
  half2v w3r[32];
  {
    half2v z; z.x = (_Float16)0; z.y = (_Float16)0;
    #pragma unroll
    for (int i = 0; i < 32; ++i) w3r[i] = z;
    if (r1 < 48){
      const half_t* wp = w3 + (size_t)(gate3*512 + m*16 + j3) * 512;
      #pragma unroll
      for (int i = 0; i < 32; ++i) w3r[i] = *(const half2v*)(wp + 2*(p + 8*i));
    }
  }
  float awr[8];
  #pragma unroll
  for (int i = 0; i < 8; ++i) awr[i] = attw[lane*8 + i];

  const int b_l = m & 3, ch = m >> 2;          // phase2 role: batch b_l, s-chunk ch
  const int bglob = b0 + b_l;
  unsigned bt = 0;

  for (int t = 0; t < Td; ++t){
    const int cur = t & 1, nxt = cur ^ 1;
    // ---------- phase 1: Ph = fc_W@h, gh = Whh@h (per group's 4 b) --------
    // hbuf was written by other blocks last step -> L1-bypass load
    ((unsigned long long*)hs)[tid] =
        ld_u64_l2(((const unsigned long long*)(hbuf + (size_t)cur*(32*512) + b0*512)) + tid);
    __syncthreads();
    {
      const half2v* h2p = (const half2v*)hs;
      float a0=0.f,a1=0.f,a2=0.f,a3=0.f;
      #pragma unroll
      for (int i = 0; i < 32; ++i){
        half2v wv = w1r[i];
        int idx = p + 8*i;
        a0 = FDOT2(wv, h2p[idx],       a0);
        a1 = FDOT2(wv, h2p[256 + idx], a1);
        a2 = FDOT2(wv, h2p[512 + idx], a2);
        a3 = FDOT2(wv, h2p[768 + idx], a3);
      }
      #pragma unroll
      for (int o = 1; o < 8; o <<= 1){
        a0 += __shfl_xor(a0, o); a1 += __shfl_xor(a1, o);
        a2 += __shfl_xor(a2, o); a3 += __shfl_xor(a3, o);
      }
      if (p == 0){
        int R = m*64 + r1;
        if (R < 512){
          ph[0*512+R]=a0; ph[1*512+R]=a1; ph[2*512+R]=a2; ph[3*512+R]=a3;
        } else {
          int Rw = R - 512;
          gh[0*1536+Rw]=a0; gh[1*1536+Rw]=a1; gh[2*1536+Rw]=a2; gh[3*1536+Rw]=a3;
        }
      }
    }
    gbar(cnt, ++bt);
    // ---------- phase 2: attention scores + chunk-local softmax partials --
    {
      const float* php = ph + b_l*512 + lane*8;
      f32x2 q0 = ld_f32x2_l2(php + 0), q1 = ld_f32x2_l2(php + 2);
      f32x2 q2 = ld_f32x2_l2(php + 4), q3 = ld_f32x2_l2(php + 6);
      float phr[8] = {q0.x,q0.y,q1.x,q1.y,q2.x,q2.y,q3.x,q3.y};
      const int w = tid >> 6;
      const int ns = (w < 2) ? 7 : 6;                      // 50 = 2*7 + 6*6
      const half_t* pbase = Penc + ((size_t)(ch*50)*32 + bglob)*512 + lane*8;
      half8v pv = *(const half8v*)(pbase + (size_t)w*16384);
      for (int k = 0; k < ns; ++k){
        int s_l = w + 8*k;
        half8v cv = pv;
        if (k + 1 < ns) pv = *(const half8v*)(pbase + (size_t)(s_l+8)*16384);
        float a = 0.f;
        #pragma unroll
        for (int i = 0; i < 8; ++i){
          float x = (float)cv[i] + phr[i];
          a = fmaf(fast_tanh(x), awr[i], a);
        }
        #pragma unroll
        for (int o = 1; o < 64; o <<= 1) a += __shfl_xor(a, o);
        if (lane == 0) es[s_l] = a;
      }
      __syncthreads();
      if (tid < 64){
        float ev = 0.f;
        if (tid < 50){
          ev = __builtin_amdgcn_exp2f((es[tid] - 20.f) * 1.4426950408889634f);
          es[tid] = ev;   // fixed-offset softmax weight (|e| <= ||att_w||_1 ~ 18)
        }
        #pragma unroll
        for (int o = 1; o < 64; o <<= 1) ev += __shfl_xor(ev, o);
        if (tid == 0) lb[b_l*8 + ch] = ev;
      }
      __syncthreads();
      float acc2 = 0.f;
      const half_t* ep = ench + ((size_t)(ch*50)*32 + bglob)*512 + tid;
      #pragma unroll 5
      for (int s_l = 0; s_l < 50; ++s_l)
        acc2 = fmaf((float)ep[(size_t)s_l*16384], es[s_l], acc2);
      pc[(b_l*8 + ch)*512 + tid] = acc2;
    }
    gbar(cnt, ++bt);
    // ---------- phase 3: combine ctx, gi_c = Wih_c@ctx, GRU update --------
    if (tid < 4){
      float L = 0.f;
      #pragma unroll
      for (int c2 = 0; c2 < 8; ++c2) L += ld_f32_l2(&lb[tid*8 + c2]);
      Ls[tid] = __builtin_amdgcn_rcpf(L);
    }
    __syncthreads();
    #pragma unroll
    for (int rep = 0; rep < 4; ++rep){
      int idx = rep*512 + tid;
      int bb = idx >> 9, hh = idx & 511;
      float v = 0.f;
      #pragma unroll
      for (int c2 = 0; c2 < 8; ++c2) v += ld_f32_l2(&pc[(bb*8 + c2)*512 + hh]);
      ctxs[bb*512 + hh] = (half_t)(v * Ls[bb]);
    }
    __syncthreads();
    if (r1 < 48){
      const half2v* cx = (const half2v*)ctxs;
      float a0=0.f,a1=0.f,a2=0.f,a3=0.f;
      #pragma unroll
      for (int i = 0; i < 32; ++i){
        half2v wv = w3r[i];
        int idx = p + 8*i;
        a0 = FDOT2(wv, cx[idx],       a0);
        a1 = FDOT2(wv, cx[256 + idx], a1);
        a2 = FDOT2(wv, cx[512 + idx], a2);
        a3 = FDOT2(wv, cx[768 + idx], a3);
      }
      #pragma unroll
      for (int o = 1; o < 8; o <<= 1){
        a0 += __shfl_xor(a0, o); a1 += __shfl_xor(a1, o);
        a2 += __shfl_xor(a2, o); a3 += __shfl_xor(a3, o);
      }
      if (p == 0){
        gis[0][gate3][j3] = a0; gis[1][gate3][j3] = a1;
        gis[2][gate3][j3] = a2; gis[3][gate3][j3] = a3;
      }
    }
    __syncthreads();
    if (tid < 64){
      int bl = tid >> 4, jl = tid & 15;
      int j = m*16 + jl;
      int bg = b0 + bl;
      const half_t* gp = gix + ((size_t)t*32 + bg)*1536;
      float xr = (float)gp[j]          + gis[bl][0][jl] + ld_f32_l2(&gh[bl*1536 + j]);
      float xz = (float)gp[512 + j]    + gis[bl][1][jl] + ld_f32_l2(&gh[bl*1536 + 512 + j]);
      float xn = (float)gp[1024 + j]   + gis[bl][2][jl];
      float gn_h = ld_f32_l2(&gh[bl*1536 + 1024 + j]);
      float r = fast_sigmoid(xr);
      float z = fast_sigmoid(xz);
      float n = fast_tanh(xn + r * gn_h);
      float hold = (float)hbuf[(size_t)cur*(32*512) + bg*512 + j];  // same thread wrote it
      float h2v = (1.f - z) * n + z * hold;
      hbuf[(size_t)nxt*(32*512) + bg*512 + j] = (half_t)h2v;
      h2a[((size_t)t*32 + bg)*512 + j] = (half_t)h2v;
    }
    gbar(cnt, ++bt);
  }
}

// ---------------- launch --------------------------------------------------
extern "C" void kernel_launch(void* const* d_in, const int* in_sizes, int n_in,
                              void* d_out, int out_size, void* d_ws, size_t ws_size,
                              hipStream_t stream)
{
  const float* dec   = (const float*)d_in[0];
  const float* enc   = (const float*)d_in[1];
  const float* fcW   = (const float*)d_in[2];
  const float* attw  = (const float*)d_in[3];
  const float* Wih   = (const float*)d_in[4];
  const float* Whh   = (const float*)d_in[5];
  const float* specW = (const float*)d_in[6];
  const float* specb = (const float*)d_in[7];
  const float* gateW = (const float*)d_in[8];
  const float* gateb = (const float*)d_in[9];
  char* ws = (char*)d_ws;
  float* out = (float*)d_out;

  hipLaunchKernelGGL(k_init, dim3(68), dim3(256), 0, stream, ws);
  hipLaunchKernelGGL(k_prep_enc, dim3(2048), dim3(256), 0, stream,
                     enc, (half_t*)(ws + OFF_ENC), Sd*Bd*Hd);
  hipLaunchKernelGGL(k_prep_xs, dim3(2048), dim3(256), 0, stream,
                     dec, (half_t*)(ws + OFF_XS));
  hipLaunchKernelGGL(k_prep_w, dim3(1024), dim3(256), 0, stream,
                     fcW, Wih, Whh, specW, ws);
  // Penc = enc @ fc_W^T   (M=12800, N=512)
  hipLaunchKernelGGL((k_gemm<0>), dim3(8, 200), dim3(256), 0, stream,
                     (const half_t*)(ws + OFF_ENC), (const half_t*)(ws + OFF_W1),
                     (void*)(ws + OFF_PENC), 512, (const float*)nullptr);
  // GI_x = xs @ Wih_x^T   (M=12800, N=1536)
  hipLaunchKernelGGL((k_gemm<0>), dim3(24, 200), dim3(256), 0, stream,
                     (const half_t*)(ws + OFF_XS), (const half_t*)(ws + OFF_WX),
                     (void*)(ws + OFF_GIX), 1536, (const float*)nullptr);
  // recurrent loop
  hipLaunchKernelGGL(k_main, dim3(256), dim3(512), 0, stream, ws, attw);
  // mels = h2 @ spec_W^T + b, written (B,T,H)
  hipLaunchKernelGGL((k_gemm<1>), dim3(8, 200), dim3(256), 0, stream,
                     (const half_t*)(ws + OFF_H2A), (const half_t*)(ws + OFF_SPEC),
                     (void*)out, 512, specb);
  // gates = h2 @ gate_W + b, written (B,T)
  hipLaunchKernelGGL(k_gate, dim3(3200), dim3(256), 0, stream,
                     (const half_t*)(ws + OFF_H2A), gateW, gateb, out);
}